// Round 19
// baseline (88.405 us; speedup 1.0000x reference)
//
#include <hip/hip_runtime.h>

// images=8, patches=3600(=60*60), hor_f=64, ver_f=25(=5*5), 64x64 px, k=5
// FUSED v2: fold+unfold per strip; FH=4, 512 blocks (2/CU); ring stride 68.
#define OH     60
#define NIMG   8
#define HF     64
#define VF     25
#define NPATCH 3600
#define CDIM   1600                  // HF*VF

typedef float floatx4 __attribute__((ext_vector_type(4)));

#define FH    4                      // h channels per block
#define FC2   100                    // FH*VF floats per patch slice
#define PJS   64                     // staged-row pj stride (XOR-swizzled)
#define SPP   15                     // patch rows emitted per strip
#define NACC  19                     // img rows accumulated (SPP+4)
#define JP2   68                     // ring col stride (68%32=4 -> bank spread)
#define ROWSZ (FH * JP2)             // 272 floats per ring slot

// grid 512 = 4 strips x 16 hg x 8 im (im = b&7 XCD-pinned), 256 threads
__global__ __launch_bounds__(256) void fused_kernel(const float* __restrict__ x,
                                                    float* __restrict__ out) {
    __shared__ float lb[FC2 * PJS];  // 25.6 KB staging
    __shared__ float li2[6 * ROWSZ]; // 6.5 KB img ring
    const int b = blockIdx.x;
    const int im = b & 7;
    const int rem = b >> 3;          // 0..63
    const int hg = rem & 15, strip = rem >> 4;
    const int t = threadIdx.x;
    const int h0 = hg * FH;
    const int pi0 = strip * SPP;
    const int j = t & 63, g = t >> 6;          // g = local h (0..3)

    const float rcj = 1.0f / (float)min(min(j + 1, 64 - j), 5);

    float acc[NACC];
#pragma unroll
    for (int k = 0; k < NACC; ++k) acc[k] = 0.f;

    const float* xb = x + (size_t)im * NPATCH * CDIM + h0 * VF;

    // staging: 60 pj x 25 f4 per patch row -> 6 slots (u = t + 256k < 1500)
    int off_g[6], off_l[6];
#pragma unroll
    for (int k = 0; k < 6; ++k) {
        int u = t + 256 * k;
        if (u < 1500) {
            int pj = u / 25, c4 = u - 25 * pj;
            off_g[k] = pj * CDIM + (c4 << 2);
            off_l[k] = (c4 << 8) + (pj ^ c4);  // element fl=4c4+c at fl*64 + (pj^c4)
        }
    }

    // emit decode (round-invariant): u -> (pj, s); fl=4s+c -> n,di,dj
    int outoff[6], colb[6][4], dic[6][4];
#pragma unroll
    for (int k = 0; k < 6; ++k) {
        int u = t + 256 * k;
        if (u < 1500) {
            int pj = u / 25, s = u - 25 * pj;
            outoff[k] = pj * CDIM + (s << 2);
#pragma unroll
            for (int c = 0; c < 4; ++c) {
                int fl = (s << 2) + c;         // = n*25 + v, < 100
                int n = fl / 25, v = fl - 25 * n;
                int di = v / 5, dj = v - 5 * di;
                colb[k][c] = n * JP2 + pj + dj;
                dic[k][c] = di;
            }
        }
    }

    float4 stg[6];
    {   // prologue: prefetch first staged row (rho = pi0-4) if it exists
        int rho = pi0 - 4;
        if (rho >= 0) {
#pragma unroll
            for (int k = 0; k < 6; ++k)
                if (t + 256 * k < 1500)
                    stg[k] = *reinterpret_cast<const float4*>(
                        xb + (size_t)rho * OH * CDIM + off_g[k]);
        }
    }

#pragma unroll
    for (int r = 0; r < 24; ++r) {
        const int rho = pi0 - 4 + r;           // patch row staged this round
        const bool sv = (r <= 22) && (rho >= 0) && (rho <= 59);

        // ---- phase 1: stage-write lb || NT-emit patch row (pi0 + r - 9) ----
        if (sv) {
#pragma unroll
            for (int k = 0; k < 6; ++k)
                if (t + 256 * k < 1500) {
                    float4 v = stg[k];
                    int a = off_l[k];
                    lb[a]           = v.x;
                    lb[a + PJS]     = v.y;
                    lb[a + 2 * PJS] = v.z;
                    lb[a + 3 * PJS] = v.w;
                }
        }
        if (r >= 9) {                          // ring rows (r-9)..(r-5) all dumped
            float* op = out + ((size_t)im * NPATCH + (size_t)(pi0 + r - 9) * OH) * CDIM
                            + h0 * VF;
            const int base = (r - 9) % 6;      // compile-time per unrolled r
#pragma unroll
            for (int k = 0; k < 6; ++k)
                if (t + 256 * k < 1500) {
                    floatx4 o;
                    { int sl = base + dic[k][0]; sl -= (sl >= 6) ? 6 : 0;
                      o.x = li2[sl * ROWSZ + colb[k][0]]; }
                    { int sl = base + dic[k][1]; sl -= (sl >= 6) ? 6 : 0;
                      o.y = li2[sl * ROWSZ + colb[k][1]]; }
                    { int sl = base + dic[k][2]; sl -= (sl >= 6) ? 6 : 0;
                      o.z = li2[sl * ROWSZ + colb[k][2]]; }
                    { int sl = base + dic[k][3]; sl -= (sl >= 6) ? 6 : 0;
                      o.w = li2[sl * ROWSZ + colb[k][3]]; }
                    __builtin_nontemporal_store(o,
                        reinterpret_cast<floatx4*>(op + outoff[k]));
                }
        }
        __syncthreads();

        // ---- phase 2: compute taps || prefetch next row || dump img row ----
        if (sv) {
#pragma unroll
            for (int di = 0; di < 5; ++di) {
                const int il = r - 4 + di;     // img row - pi0 (compile-time)
                if (il >= 0 && il < NACC) {
#pragma unroll
                    for (int dj = 0; dj < 5; ++dj) {
                        int c = g * VF + di * 5 + dj;
                        int pjr = j - dj;
                        if ((unsigned)pjr < 60u)
                            acc[il] += lb[c * PJS + (pjr ^ (c >> 2))];
                    }
                }
            }
        }
        if (r + 1 <= 22) {                     // prefetch row rho+1 during compute
            int rho2 = rho + 1;
            if (rho2 >= 0 && rho2 <= 59) {
#pragma unroll
                for (int k = 0; k < 6; ++k)
                    if (t + 256 * k < 1500)
                        stg[k] = *reinterpret_cast<const float4*>(
                            xb + (size_t)rho2 * OH * CDIM + off_g[k]);
            }
        }
        if (r >= 4 && r <= 22) {               // img row pi0+r-4 complete -> ring
            const int il = r - 4;              // compile-time
            const int i = pi0 + il;
            float ri = 0.2f;
            if (i < 4) ri = 1.0f / (float)(i + 1);
            else if (i > 59) ri = 1.0f / (float)(64 - i);
            li2[(il % 6) * ROWSZ + g * JP2 + j] = acc[il] * ri * rcj;
        }
        __syncthreads();
    }
}

extern "C" void kernel_launch(void* const* d_in, const int* in_sizes, int n_in,
                              void* d_out, int out_size, void* d_ws, size_t ws_size,
                              hipStream_t stream) {
    const float* x = (const float*)d_in[0];
    float* out = (float*)d_out;

    fused_kernel<<<512, 256, 0, stream>>>(x, out);   // 4 strips x 16 hg x 8 im

    (void)out_size; (void)ws_size; (void)d_ws; (void)in_sizes; (void)n_in;
}

// Round 20
// 77.829 us; speedup vs baseline: 1.1359x; 1.1359x over previous
//
#include <hip/hip_runtime.h>

// images=8, patches=3600(=60*60), hor_f=64, ver_f=25(=5*5), 64x64 px, k=5
#define OH     60
#define NIMG   8
#define HF     64
#define VF     25
#define NPATCH 3600
#define CDIM   1600                  // HF*VF

typedef float floatx4 __attribute__((ext_vector_type(4)));  // native vec for nt-store

// ---- fold v3 (BARRIER-FREE): 1D grid 768, XCD-pinned; wave-private channels ----
// Wave g owns channel h0+g exclusively: stages its own 60x25 row slice into a
// private LDS region and computes without any __syncthreads (intra-wave order
// only). 24 independent wave-streams/CU replace the 5-round barrier lockstep.
#define FH   8                       // h channels per block = waves per block
#define SPI  5                       // pi rows per strip
#define NSTRIP 12
#define SROWS  9                     // SPI + 4 halo rows
#define NF   1500                    // floats per wave-row: 60 pj x 25 v (pj-major)
#define WSTR 1536                    // wave LDS slice stride (floats)

__global__ __launch_bounds__(512, 6) void fold_kernel(const float* __restrict__ x,
                                                      float* __restrict__ slab) {
    __shared__ float lb[FH * WSTR];  // 8 x 1536 fl = 49.2 KB
    const int b = blockIdx.x;
    const int im = b & 7;            // XCD pin
    const int rem = b >> 3;          // 0..95
    const int hg = rem & 7, strip = rem >> 3;
    const int t = threadIdx.x;
    const int h0 = hg * FH;
    const int pi0 = strip * SPI;
    const int j = t & 63, g = t >> 6;          // g = wave = local channel

    float* lbw = lb + g * WSTR;      // wave-private slice

    float acc[SROWS];
#pragma unroll
    for (int k = 0; k < SROWS; ++k) acc[k] = 0.f;

    // channel base: x[im][pi0*60 + pj][h0+g][v]
    const float* xb = x + ((size_t)im * NPATCH + (size_t)pi0 * OH) * CDIM
                        + (h0 + g) * VF;

    // row-invariant global offsets for staging slot s: u = j + 64s -> (pj, v)
    int off_g[24];
#pragma unroll
    for (int s = 0; s < 24; ++s) {
        int u = j + 64 * s;
        if (u < NF) {
            int pj = u / 25, v = u - 25 * pj;
            off_g[s] = pj * CDIM + v;
        }
    }

    for (int row = 0; row < SPI; ++row) {
        const float* xr = xb + (size_t)row * OH * CDIM;
        // stage own channel row: coalesced scalar loads -> identity LDS layout
#pragma unroll
        for (int s = 0; s < 24; ++s) {
            int u = j + 64 * s;
            if (u < NF) lbw[u] = xr[off_g[s]];
        }
        // compute 25 taps for column j (intra-wave dependency only)
#pragma unroll
        for (int dj = 0; dj < 5; ++dj) {
            int pjr = j - dj;
            bool ok = (unsigned)pjr < 60u;
            const float* pcol = lbw + pjr * 25;
#pragma unroll
            for (int di = 0; di < 5; ++di) {
                if (ok) acc[row + di] += pcol[di * 5 + dj];
            }
        }
    }

    // epilogue: 9 coalesced stores, disjoint slab region (channel h0+g)
    float* sb = slab + (((size_t)(strip * 8 + im) * 64 + h0 + g) * SROWS) * 64 + j;
#pragma unroll
    for (int il = 0; il < SROWS; ++il) sb[il * 64] = acc[il];
}

// ---- unfold (r15 verbatim): 1D grid 1920, XCD-pinned, NT stores ----
#define UH   16                      // channels per block
#define LJS  68                      // padded j stride (f4-aligned)

__global__ __launch_bounds__(256) void unfold_kernel(const float* __restrict__ slab,
                                                     float* __restrict__ out) {
    __shared__ float li[UH * 5 * LJS];         // 5440 fl = 21.76 KB
    __shared__ int4 lut[100];
    const int b = blockIdx.x;
    const int im = b & 7;            // XCD pin
    const int rem = b >> 3;          // 0..239
    const int hh = rem & 3, pi = rem >> 2;     // hh 0..3, pi 0..59
    const int t = threadIdx.x;
    const int h0 = hh * UH;

    if (t < 100) {                             // f4-slot r -> 4 LDS offsets (R*LJS+dj)
        int4 e;
        int* ep = &e.x;
#pragma unroll
        for (int k = 0; k < 4; ++k) {
            int fl = 4 * t + k;                // = ho*25 + v
            int ho = fl / 25, v = fl - 25 * ho;
            int di = v / 5, dj = v - 5 * di;
            ep[k] = (ho * 5 + di) * LJS + dj;
        }
        lut[t] = e;
    }

    // stage rows pi..pi+4 of 16 channels (strip-summed), pre-scaled by 1/(ci*cj)
    for (int u = t; u < UH * 5 * 16; u += 256) {
        int ch = u / 80, rem2 = u - 80 * ch;
        int di = rem2 >> 4, j4 = rem2 & 15;
        int i = pi + di;
        int s_hi = min(i / 5, NSTRIP - 1);
        int s_lo = (i <= 8) ? 0 : (i - 4) / 5;
        const float* pa = slab +
            (((size_t)(s_lo * 8 + im) * 64 + h0 + ch) * SROWS + (i - 5 * s_lo)) * 64 + (j4 << 2);
        float4 v = *reinterpret_cast<const float4*>(pa);
        if (s_hi != s_lo) {
            const float* pb = slab +
                (((size_t)(s_hi * 8 + im) * 64 + h0 + ch) * SROWS + (i - 5 * s_hi)) * 64 + (j4 << 2);
            float4 w = *reinterpret_cast<const float4*>(pb);
            v.x += w.x; v.y += w.y; v.z += w.z; v.w += w.w;
        }
        float ri = 1.0f / (float)min(min(i + 1, 64 - i), 5);
        int jb = j4 << 2;
        float4 w;
        w.x = v.x * ri * (1.0f / (float)min(min(jb + 1, 64 - jb), 5));
        w.y = v.y * ri * (1.0f / (float)min(min(jb + 2, 63 - jb), 5));
        w.z = v.z * ri * (1.0f / (float)min(min(jb + 3, 62 - jb), 5));
        w.w = v.w * ri * (1.0f / (float)min(min(jb + 4, 61 - jb), 5));
        *reinterpret_cast<float4*>(&li[(ch * 5 + di) * LJS + jb]) = w;
    }
    __syncthreads();

    // emit: 60 pj x 100 float4, LUT-addressed, NON-TEMPORAL coalesced writes
    float* ob = out + ((size_t)im * NPATCH + (size_t)pi * OH) * CDIM + h0 * VF;
    for (int u = t; u < 6000; u += 256) {
        int pj = u / 100, r = u - 100 * pj;
        int4 e = lut[r];
        floatx4 o;
        o.x = li[e.x + pj];
        o.y = li[e.y + pj];
        o.z = li[e.z + pj];
        o.w = li[e.w + pj];
        __builtin_nontemporal_store(o,
            reinterpret_cast<floatx4*>(ob + (size_t)pj * CDIM + 4 * r));
    }
}

extern "C" void kernel_launch(void* const* d_in, const int* in_sizes, int n_in,
                              void* d_out, int out_size, void* d_ws, size_t ws_size,
                              hipStream_t stream) {
    const float* x = (const float*)d_in[0];
    float* slab = (float*)d_ws;                // 12*8*64*9*64 fl = 14.2 MB
    float* out  = (float*)d_out;

    fold_kernel<<<768, 512, 0, stream>>>(x, slab);      // 96 blocks per image/XCD
    unfold_kernel<<<1920, 256, 0, stream>>>(slab, out); // 240 blocks per image/XCD

    (void)out_size; (void)ws_size; (void)in_sizes; (void)n_in;
}

// Round 21
// 76.388 us; speedup vs baseline: 1.1573x; 1.0189x over previous
//
#include <hip/hip_runtime.h>

// images=8, patches=3600(=60*60), hor_f=64, ver_f=25(=5*5), 64x64 px, k=5
// FINAL (r15 config): fold->slab->unfold, XCD-pinned grids, NT out stores.
// Measured: fold ~33us (L3-read floor), unfold ~40us (NT-write floor), 76.2us.
#define OH     60
#define NIMG   8
#define HF     64
#define VF     25
#define NPATCH 3600
#define CDIM   1600                  // HF*VF

typedef float floatx4 __attribute__((ext_vector_type(4)));  // native vec for nt-store

// ---- fold: 1D grid 768, XCD-pinned: im = b & 7 ----
#define FH   8                       // h channels per block
#define FC   (FH * VF)               // 200 c values
#define SPI  5                       // pi rows per strip
#define PJS  64                      // pj stride (XOR-swizzled)
#define NSTRIP 12
#define SROWS  9                     // SPI + 4 halo rows

__global__ __launch_bounds__(512, 6) void fold_kernel(const float* __restrict__ x,
                                                      float* __restrict__ slab) {
    __shared__ float lb[FC * PJS];   // 51.2 KB
    const int b = blockIdx.x;
    const int im = b & 7;            // XCD pin (blockIdx round-robins mod 8)
    const int rem = b >> 3;          // 0..95
    const int hg = rem & 7, strip = rem >> 3;
    const int t = threadIdx.x;
    const int h0 = hg * FH;
    const int pi0 = strip * SPI;
    const int j = t & 63, g = t >> 6;          // g = local h (0..7)

    float acc[SROWS];
#pragma unroll
    for (int k = 0; k < SROWS; ++k) acc[k] = 0.f;

    const float* xb = x + ((size_t)im * NPATCH + (size_t)pi0 * OH) * CDIM + h0 * VF;

    int off_g[6], off_l[6];
#pragma unroll
    for (int k = 0; k < 6; ++k) {
        int u = t + 512 * k;
        if (u < 3000) {
            int pj = u / 50, c4 = u - 50 * pj;
            off_g[k] = pj * CDIM + (c4 << 2);
            off_l[k] = (c4 << 8) + (pj ^ (c4 & 31));
        }
    }

    float4 stg[6];
#pragma unroll
    for (int k = 0; k < 6; ++k)
        if (t + 512 * k < 3000)
            stg[k] = *reinterpret_cast<const float4*>(xb + off_g[k]);

#pragma unroll
    for (int row = 0; row < SPI; ++row) {
        if (row) __syncthreads();
#pragma unroll
        for (int k = 0; k < 6; ++k)
            if (t + 512 * k < 3000) {
                float4 v = stg[k];
                int a = off_l[k];
                lb[a]           = v.x;
                lb[a + PJS]     = v.y;
                lb[a + 2 * PJS] = v.z;
                lb[a + 3 * PJS] = v.w;
            }
        if (row + 1 < SPI) {                   // prefetch next row during compute
#pragma unroll
            for (int k = 0; k < 6; ++k)
                if (t + 512 * k < 3000)
                    stg[k] = *reinterpret_cast<const float4*>(
                        xb + (size_t)(row + 1) * OH * CDIM + off_g[k]);
        }
        __syncthreads();
#pragma unroll
        for (int di = 0; di < 5; ++di) {
#pragma unroll
            for (int dj = 0; dj < 5; ++dj) {
                int c = g * VF + di * 5 + dj;
                int pjr = j - dj;
                if ((unsigned)pjr < 60u)
                    acc[row + di] += lb[c * PJS + (pjr ^ ((c >> 2) & 31))];
            }
        }
    }

    float* sb = slab + (((size_t)(strip * 8 + im) * 64 + h0 + g) * SROWS) * 64 + j;
#pragma unroll
    for (int il = 0; il < SROWS; ++il) sb[il * 64] = acc[il];
}

// ---- unfold: 1D grid 1920, XCD-pinned, NT stores ----
#define UH   16                      // channels per block
#define LJS  68                      // padded j stride (f4-aligned)

__global__ __launch_bounds__(256) void unfold_kernel(const float* __restrict__ slab,
                                                     float* __restrict__ out) {
    __shared__ float li[UH * 5 * LJS];         // 5440 fl = 21.76 KB
    __shared__ int4 lut[100];
    const int b = blockIdx.x;
    const int im = b & 7;            // XCD pin
    const int rem = b >> 3;          // 0..239
    const int hh = rem & 3, pi = rem >> 2;     // hh 0..3, pi 0..59
    const int t = threadIdx.x;
    const int h0 = hh * UH;

    if (t < 100) {                             // f4-slot r -> 4 LDS offsets (R*LJS+dj)
        int4 e;
        int* ep = &e.x;
#pragma unroll
        for (int k = 0; k < 4; ++k) {
            int fl = 4 * t + k;                // = ho*25 + v
            int ho = fl / 25, v = fl - 25 * ho;
            int di = v / 5, dj = v - 5 * di;
            ep[k] = (ho * 5 + di) * LJS + dj;
        }
        lut[t] = e;
    }

    // stage rows pi..pi+4 of 16 channels (strip-summed), pre-scaled by 1/(ci*cj)
    for (int u = t; u < UH * 5 * 16; u += 256) {
        int ch = u / 80, rem2 = u - 80 * ch;
        int di = rem2 >> 4, j4 = rem2 & 15;
        int i = pi + di;
        int s_hi = min(i / 5, NSTRIP - 1);
        int s_lo = (i <= 8) ? 0 : (i - 4) / 5;
        const float* pa = slab +
            (((size_t)(s_lo * 8 + im) * 64 + h0 + ch) * SROWS + (i - 5 * s_lo)) * 64 + (j4 << 2);
        float4 v = *reinterpret_cast<const float4*>(pa);
        if (s_hi != s_lo) {
            const float* pb = slab +
                (((size_t)(s_hi * 8 + im) * 64 + h0 + ch) * SROWS + (i - 5 * s_hi)) * 64 + (j4 << 2);
            float4 w = *reinterpret_cast<const float4*>(pb);
            v.x += w.x; v.y += w.y; v.z += w.z; v.w += w.w;
        }
        float ri = 1.0f / (float)min(min(i + 1, 64 - i), 5);
        int jb = j4 << 2;
        float4 w;
        w.x = v.x * ri * (1.0f / (float)min(min(jb + 1, 64 - jb), 5));
        w.y = v.y * ri * (1.0f / (float)min(min(jb + 2, 63 - jb), 5));
        w.z = v.z * ri * (1.0f / (float)min(min(jb + 3, 62 - jb), 5));
        w.w = v.w * ri * (1.0f / (float)min(min(jb + 4, 61 - jb), 5));
        *reinterpret_cast<float4*>(&li[(ch * 5 + di) * LJS + jb]) = w;
    }
    __syncthreads();

    // emit: 60 pj x 100 float4, LUT-addressed, NON-TEMPORAL coalesced writes.
    // nt keeps out (never re-read) from evicting x+slab in L3 across replays.
    float* ob = out + ((size_t)im * NPATCH + (size_t)pi * OH) * CDIM + h0 * VF;
    for (int u = t; u < 6000; u += 256) {
        int pj = u / 100, r = u - 100 * pj;
        int4 e = lut[r];
        floatx4 o;
        o.x = li[e.x + pj];
        o.y = li[e.y + pj];
        o.z = li[e.z + pj];
        o.w = li[e.w + pj];
        __builtin_nontemporal_store(o,
            reinterpret_cast<floatx4*>(ob + (size_t)pj * CDIM + 4 * r));
    }
}

extern "C" void kernel_launch(void* const* d_in, const int* in_sizes, int n_in,
                              void* d_out, int out_size, void* d_ws, size_t ws_size,
                              hipStream_t stream) {
    const float* x = (const float*)d_in[0];
    float* slab = (float*)d_ws;                // 12*8*64*9*64 fl = 14.2 MB
    float* out  = (float*)d_out;

    fold_kernel<<<768, 512, 0, stream>>>(x, slab);      // 96 blocks per image/XCD
    unfold_kernel<<<1920, 256, 0, stream>>>(slab, out); // 240 blocks per image/XCD

    (void)out_size; (void)ws_size; (void)in_sizes; (void)n_in;
}